// Round 5
// baseline (193.815 us; speedup 1.0000x reference)
//
#include <hip/hip_runtime.h>
#include <math.h>

#define Bb 256
#define Tt 256
#define Ee 384
#define Hh 64

typedef __attribute__((ext_vector_type(8))) short bf16x8;
typedef __attribute__((ext_vector_type(4))) float f32x4;
typedef __attribute__((ext_vector_type(4))) unsigned int u32x4;

__device__ inline short f2bf(float f) {
    unsigned u = __float_as_uint(f);
    u += 0x7FFFu + ((u >> 16) & 1);      // RNE
    return (short)(u >> 16);
}
__device__ inline float bf2f(short s) {
    return __uint_as_float(((unsigned)(unsigned short)s) << 16);
}
// packed f32x2 -> bf16x2 (RNE). D[15:0]=bf16(a), D[31:16]=bf16(b)
__device__ inline unsigned cvt_pk_bf16(float a, float b) {
    unsigned r;
    asm("v_cvt_pk_bf16_f32 %0, %1, %2" : "=v"(r) : "v"(a), "v"(b));
    return r;
}

#define MFMA16(a, b, c) __builtin_amdgcn_mfma_f32_16x16x32_bf16((a), (b), (c), 0, 0, 0)

// ---- W fragment buffer in d_ws: hi at 0, lo at 147456; frag (ec*12+tct)*1024 ----
#define WLO_OFF 147456

// ---- split-path ws layout: QKV regions after the W frags ----
// per batch (SB=160KB): KHI 0 | KLO 32768 | VV 65536 | QHI 98304 | QLO 131072
#define WQKV 294912
#define SB   163840
#define WS_NEED (294912ull + 256ull * 163840ull)

// ---- fused-path LDS offsets (fallback kernel) ----
#define BB0 65536
#define K_HI 0
#define K_LO 32768
#define VF   65536
#define QH   98304
#define QL   116736
#define PBASE 98304
#define SMEM_BYTES 135168

// ============ prep kernel: W -> bf16 hi/lo in B-fragment layout (coalesced) ============
__global__ __launch_bounds__(256) void prep_w(
    const float* __restrict__ Wq, const float* __restrict__ Wk,
    const float* __restrict__ Wv, unsigned char* __restrict__ wsp)
{
    __shared__ float wlds[32 * 66];
    const int bid = blockIdx.x;                // 0..35
    const int ec  = bid / 3, m = bid - ec * 3;
    const float* Wm = (m == 0) ? Wq : (m == 1 ? Wk : Wv);
    const int tid = threadIdx.x;

    const float4* src = reinterpret_cast<const float4*>(Wm + ec * 2048) + tid * 2;
    float4 a = src[0], b = src[1];
    int f = tid * 8;
    float* d = wlds + (f >> 6) * 66 + (f & 63);
    d[0] = a.x; d[1] = a.y; d[2] = a.z; d[3] = a.w;
    d[4] = b.x; d[5] = b.y; d[6] = b.z; d[7] = b.w;
    __syncthreads();

    const int tl = tid >> 6, lu = tid & 63;
    const int koct = lu >> 4, n = lu & 15;
    const int c = tl * 16 + n;
    bf16x8 hi8, lo8;
    #pragma unroll
    for (int j = 0; j < 8; ++j) {
        float v = wlds[(koct * 8 + j) * 66 + c];
        short h = f2bf(v);
        hi8[j] = h;
        lo8[j] = f2bf(v - bf2f(h));
    }
    const int frag = ec * 12 + m * 4 + tl;
    *reinterpret_cast<bf16x8*>(wsp + frag * 1024 + lu * 16) = hi8;
    *reinterpret_cast<bf16x8*>(wsp + WLO_OFF + frag * 1024 + lu * 16) = lo8;
}

// ============ split kernel 1: QKV projection, 2 blocks/CU ============
// block = (batch, half): 128 rows x 192 cols. 8 waves: ri=w>>1 (rowtiles 2ri,2ri+1),
// cj=w&1 (coltiles 6cj..6cj+5). LDS: A dbuf 2x16K at 0, B dbuf 2x24K at 32768 = 80KB.
#define BBA 32768
__global__ __launch_bounds__(512, 4) void qkv_proj(
    const float* __restrict__ x,
    const float* __restrict__ bq, const float* __restrict__ bk,
    const float* __restrict__ bv,
    const unsigned char* __restrict__ wsp,
    unsigned char* __restrict__ qkvws)
{
    __shared__ __align__(16) unsigned char smem[81920];

    const int bid  = blockIdx.x;       // 0..511
    const int b    = bid >> 1;
    const int half = bid & 1;
    const int tid  = threadIdx.x;
    const int w    = tid >> 6;         // 0..7
    const int lane = tid & 63;
    const int quad = lane >> 4;
    const int nl   = lane & 15;
    const int ri   = w >> 1;           // 0..3
    const int cj   = w & 1;            // 0..1

    f32x4 acc[2][6];
    #pragma unroll
    for (int i = 0; i < 2; ++i)
        #pragma unroll
        for (int j = 0; j < 6; ++j) acc[i][j] = (f32x4){0,0,0,0};

    const float4* x4 = reinterpret_cast<const float4*>(x + (size_t)b * Tt * Ee);

    // B-frag DMA: waves 0..5 move frags {2w,2w+1} hi+lo per ec.
    auto bgld = [&](int ecn) {
        if (w < 6) {
            int p = ecn & 1;
            int f0 = w * 2;
            const unsigned char* g0 = wsp + (size_t)(ecn * 12 + f0) * 1024 + (size_t)lane * 16;
            unsigned char* d0 = smem + BBA + p * 24576 + f0 * 1024;
            __builtin_amdgcn_global_load_lds(
                (const __attribute__((address_space(1))) unsigned*)g0,
                (__attribute__((address_space(3))) unsigned*)d0, 16, 0, 0);
            __builtin_amdgcn_global_load_lds(
                (const __attribute__((address_space(1))) unsigned*)(g0 + 1024),
                (__attribute__((address_space(3))) unsigned*)(d0 + 1024), 16, 0, 0);
            __builtin_amdgcn_global_load_lds(
                (const __attribute__((address_space(1))) unsigned*)(g0 + WLO_OFF),
                (__attribute__((address_space(3))) unsigned*)(d0 + 12288), 16, 0, 0);
            __builtin_amdgcn_global_load_lds(
                (const __attribute__((address_space(1))) unsigned*)(g0 + WLO_OFF + 1024),
                (__attribute__((address_space(3))) unsigned*)(d0 + 12288 + 1024), 16, 0, 0);
        }
    };

    // A staging: waves 6,7 (128 threads), thread owns local row pt; R2 pattern
    // (load+convert+write in one shot at body top; latency hidden by other waves).
    const int pt = tid & 127;
    const float4* xp = x4 + (half * 128 + pt) * 96;
    unsigned char* adst = smem + (pt >> 4) * 1024 + (pt & 15) * 16;

    auto stageA = [&](int ecsrc, int nb) {
        float4 px[8];
        const float4* xr_ = xp + ecsrc * 8;
        #pragma unroll
        for (int j = 0; j < 8; ++j) px[j] = xr_[j];
        #pragma unroll
        for (int ko = 0; ko < 4; ++ko) {
            float v0 = px[2*ko+0].x, v1 = px[2*ko+0].y,
                  v2 = px[2*ko+0].z, v3 = px[2*ko+0].w,
                  v4 = px[2*ko+1].x, v5 = px[2*ko+1].y,
                  v6 = px[2*ko+1].z, v7 = px[2*ko+1].w;
            unsigned h0 = cvt_pk_bf16(v0, v1);
            unsigned h1 = cvt_pk_bf16(v2, v3);
            unsigned h2 = cvt_pk_bf16(v4, v5);
            unsigned h3 = cvt_pk_bf16(v6, v7);
            unsigned l0 = cvt_pk_bf16(v0 - __uint_as_float(h0 << 16),
                                      v1 - __uint_as_float(h0 & 0xFFFF0000u));
            unsigned l1 = cvt_pk_bf16(v2 - __uint_as_float(h1 << 16),
                                      v3 - __uint_as_float(h1 & 0xFFFF0000u));
            unsigned l2 = cvt_pk_bf16(v4 - __uint_as_float(h2 << 16),
                                      v5 - __uint_as_float(h2 & 0xFFFF0000u));
            unsigned l3 = cvt_pk_bf16(v6 - __uint_as_float(h3 << 16),
                                      v7 - __uint_as_float(h3 & 0xFFFF0000u));
            u32x4 hv = {h0, h1, h2, h3};
            u32x4 lv = {l0, l1, l2, l3};
            *reinterpret_cast<u32x4*>(adst + nb + ko * 256) = hv;
            *reinterpret_cast<u32x4*>(adst + nb + 8192 + ko * 256) = lv;
        }
    };

    // preloop
    bgld(0);
    if (w >= 6) stageA(0, 0);

    for (int ec = 0; ec < 12; ++ec) {
        __syncthreads();
        if (w < 6) {
            if (ec < 11) bgld(ec + 1);
        } else {
            if (ec < 11) stageA(ec + 1, (1 - (ec & 1)) * 16384);
        }

        const int ab = (ec & 1) * 16384;
        const int bb = BBA + (ec & 1) * 24576;
        bf16x8 bh[6], bl[6];
        #pragma unroll
        for (int ct = 0; ct < 6; ++ct) {
            int o = bb + (cj * 6 + ct) * 1024 + lane * 16;
            bh[ct] = *reinterpret_cast<bf16x8*>(smem + o);
            bl[ct] = *reinterpret_cast<bf16x8*>(smem + o + 12288);
        }
        __builtin_amdgcn_s_setprio(1);
        #pragma unroll
        for (int rt = 0; rt < 2; ++rt) {
            int ao = ab + (ri * 2 + rt) * 1024 + lane * 16;
            bf16x8 ah = *reinterpret_cast<bf16x8*>(smem + ao);
            bf16x8 al = *reinterpret_cast<bf16x8*>(smem + ao + 8192);
            #pragma unroll
            for (int ct = 0; ct < 6; ++ct) {
                acc[rt][ct] = MFMA16(ah, bh[ct], acc[rt][ct]);
                acc[rt][ct] = MFMA16(al, bh[ct], acc[rt][ct]);
                acc[rt][ct] = MFMA16(ah, bl[ct], acc[rt][ct]);
            }
        }
        __builtin_amdgcn_s_setprio(0);
    }
    __syncthreads();   // staging buffers dead; smem becomes the out-shard

    // bias fold
    #pragma unroll
    for (int ct = 0; ct < 6; ++ct) {
        int col = (cj * 6 + ct) * 16 + nl;
        float bias = (col < 64) ? bq[col] : (col < 128 ? bk[col - 64] : bv[col - 128]);
        #pragma unroll
        for (int rt = 0; rt < 2; ++rt)
            #pragma unroll
            for (int r = 0; r < 4; ++r) acc[rt][ct][r] += bias;
    }

    // scatter this half's K/V/Q shard into LDS (local row sl = 0..127)
    // shard: KHI 0 | KLO 16384 | V 32768 | QHI 49152 | QLO 65536  (5 x 16KB)
    #pragma unroll
    for (int ct = 0; ct < 6; ++ct) {
        int col = (cj * 6 + ct) * 16 + nl;
        #pragma unroll
        for (int rt = 0; rt < 2; ++rt) {
            #pragma unroll
            for (int r = 0; r < 4; ++r) {
                float val = acc[rt][ct][r];
                int sl = ri * 32 + rt * 16 + quad * 4 + r;
                if (col < 64) {
                    short hi = f2bf(val);
                    short lo = f2bf(val - bf2f(hi));
                    int qaddr = (sl * 64 + col) * 2;
                    *reinterpret_cast<short*>(smem + 49152 + qaddr) = hi;
                    *reinterpret_cast<short*>(smem + 65536 + qaddr) = lo;
                } else if (col < 128) {
                    int h = col - 64;
                    int addr = ((sl >> 4) * 2 + (h >> 5)) * 1024
                             + ((((h & 31) >> 3) * 16 + (sl & 15)) * 8 + (h & 7)) * 2;
                    short hi = f2bf(val);
                    short lo = f2bf(val - bf2f(hi));
                    *reinterpret_cast<short*>(smem + addr) = hi;
                    *reinterpret_cast<short*>(smem + 16384 + addr) = lo;
                } else {
                    int h = col - 128, sll = sl & 31;
                    int addr = ((sl >> 5) * 4 + (h >> 4)) * 1024
                             + (((sll >> 3) * 16 + (h & 15)) * 8 + (sll & 7)) * 2;
                    *reinterpret_cast<short*>(smem + 32768 + addr) = f2bf(val);
                }
            }
        }
    }
    __syncthreads();

    // coalesced copy-out: 5 x 16KB LDS regions -> ws regions (+half*16384 each)
    unsigned char* dstb = qkvws + (size_t)b * SB;
    #pragma unroll
    for (int it = 0; it < 10; ++it) {
        int L = it * 8192 + tid * 16;
        u32x4 v = *reinterpret_cast<u32x4*>(smem + L);
        *reinterpret_cast<u32x4*>(dstb + (L >> 14) * 32768 + half * 16384 + (L & 16383)) = v;
    }
}

// ============ split kernel 2: causal attention, K/V/Q from ws (L2/L3) ============
// block = (batch, half); 8 waves; wave w owns global rows 16*(half*8+w)..+15.
// LDS: only the P round-trip buffer (8 x 1344 B).
__global__ __launch_bounds__(512, 4) void attn(
    const unsigned char* __restrict__ qkvws, float* __restrict__ out)
{
    __shared__ __align__(16) unsigned char smem[10752];

    const int bid  = blockIdx.x;
    const int b    = bid >> 1;
    const int half = bid & 1;
    const int tid  = threadIdx.x;
    const int w    = tid >> 6;
    const int lane = tid & 63;
    const int quad = lane >> 4;
    const int nl   = lane & 15;
    const int g    = half * 8 + w;
    const int t0   = g * 16;

    const unsigned char* kvq = qkvws + (size_t)b * SB;
    const unsigned char* KHg = kvq;
    const unsigned char* KLg = kvq + 32768;
    const unsigned char* VVg = kvq + 65536;
    const unsigned char* QHg = kvq + 98304;
    const unsigned char* QLg = kvq + 131072;

    // Q fragments: row t0+nl, k-slice quad*8 (qh0/ql0: k 0..31, qh1/ql1: k 32..63)
    const int qb = (t0 + nl) * 128 + quad * 16;
    bf16x8 qh0 = *reinterpret_cast<const bf16x8*>(QHg + qb);
    bf16x8 qh1 = *reinterpret_cast<const bf16x8*>(QHg + qb + 64);
    bf16x8 ql0 = *reinterpret_cast<const bf16x8*>(QLg + qb);
    bf16x8 ql1 = *reinterpret_cast<const bf16x8*>(QLg + qb + 64);

    f32x4 oacc[4];
    #pragma unroll
    for (int i = 0; i < 4; ++i) oacc[i] = (f32x4){0,0,0,0};
    float lsum4[4] = {0.f, 0.f, 0.f, 0.f};
    unsigned char* pb = smem + w * 1344;
    const int npairs = (g >> 1) + 1;

    bf16x8 kA0, kA1, kA2, kA3, kB0, kB1, kB2, kB3;
#define LDK(P) do {                                                       \
        int kb_ = (2 * (P)) * 2048 + lane * 16;                           \
        kA0 = *reinterpret_cast<const bf16x8*>(KHg + kb_);                \
        kA1 = *reinterpret_cast<const bf16x8*>(KHg + kb_ + 1024);         \
        kA2 = *reinterpret_cast<const bf16x8*>(KLg + kb_);                \
        kA3 = *reinterpret_cast<const bf16x8*>(KLg + kb_ + 1024);         \
        kB0 = *reinterpret_cast<const bf16x8*>(KHg + kb_ + 2048);         \
        kB1 = *reinterpret_cast<const bf16x8*>(KHg + kb_ + 3072);         \
        kB2 = *reinterpret_cast<const bf16x8*>(KLg + kb_ + 2048);         \
        kB3 = *reinterpret_cast<const bf16x8*>(KLg + kb_ + 3072);         \
    } while (0)

    LDK(0);
    for (int p = 0; p < npairs; ++p) {
        f32x4 sa0 = (f32x4){0,0,0,0}, sa1 = (f32x4){0,0,0,0};
        f32x4 sb0 = (f32x4){0,0,0,0}, sb1 = (f32x4){0,0,0,0};
        __builtin_amdgcn_s_setprio(1);
        sa0 = MFMA16(qh0, kA0, sa0);  sb0 = MFMA16(qh0, kB0, sb0);
        sa1 = MFMA16(qh1, kA1, sa1);  sb1 = MFMA16(qh1, kB1, sb1);
        sa0 = MFMA16(ql0, kA0, sa0);  sb0 = MFMA16(ql0, kB0, sb0);
        sa1 = MFMA16(ql1, kA1, sa1);  sb1 = MFMA16(ql1, kB1, sb1);
        sa0 = MFMA16(qh0, kA2, sa0);  sb0 = MFMA16(qh0, kB2, sb0);
        sa1 = MFMA16(qh1, kA3, sa1);  sb1 = MFMA16(qh1, kB3, sb1);
        __builtin_amdgcn_s_setprio(0);

        float rs[4];
        const int sg0 = 32 * p + nl, sg1 = sg0 + 16;
        #pragma unroll
        for (int r = 0; r < 4; ++r) {
            int tg = t0 + quad * 4 + r;
            float sva = sa0[r] + sa1[r];
            float svb = sb0[r] + sb1[r];
            float pva = (sg0 <= tg) ? __expf(sva) : 0.f;
            float pvb = (sg1 <= tg) ? __expf(svb) : 0.f;
            rs[r] = pva + pvb;
            *reinterpret_cast<short*>(pb + ((quad * 4 + r) * 40 + nl) * 2)      = f2bf(pva);
            *reinterpret_cast<short*>(pb + ((quad * 4 + r) * 40 + 16 + nl) * 2) = f2bf(pvb);
        }
        asm volatile("" ::: "memory");   // pin issue order: P-writes before P-read
        bf16x8 pa  = *reinterpret_cast<bf16x8*>(pb + (nl * 40 + quad * 8) * 2);
        int vb = p * 4096 + lane * 16;
        bf16x8 vf0 = *reinterpret_cast<const bf16x8*>(VVg + vb);
        bf16x8 vf1 = *reinterpret_cast<const bf16x8*>(VVg + vb + 1024);
        bf16x8 vf2 = *reinterpret_cast<const bf16x8*>(VVg + vb + 2048);
        bf16x8 vf3 = *reinterpret_cast<const bf16x8*>(VVg + vb + 3072);
        if (p + 1 < npairs) LDK(p + 1);

        #pragma unroll
        for (int r = 0; r < 4; ++r) {
            float v = rs[r];
            v += __shfl_xor(v, 1);
            v += __shfl_xor(v, 2);
            v += __shfl_xor(v, 4);
            v += __shfl_xor(v, 8);
            lsum4[r] += v;
        }
        __builtin_amdgcn_s_setprio(1);
        oacc[0] = MFMA16(pa, vf0, oacc[0]);
        oacc[1] = MFMA16(pa, vf1, oacc[1]);
        oacc[2] = MFMA16(pa, vf2, oacc[2]);
        oacc[3] = MFMA16(pa, vf3, oacc[3]);
        __builtin_amdgcn_s_setprio(0);
    }
#undef LDK

    float* ob = out + (size_t)b * Tt * Hh + (size_t)t0 * Hh;
    #pragma unroll
    for (int r = 0; r < 4; ++r) {
        float inv = 1.0f / lsum4[r];
        #pragma unroll
        for (int nt = 0; nt < 4; ++nt)
            ob[(quad * 4 + r) * 64 + nt * 16 + nl] = oacc[nt][r] * inv;
    }
}

// ============ fallback: R4 fused kernel (used when ws too small) ============
__global__ __launch_bounds__(1024) void head_fused(
    const float* __restrict__ x,
    const float* __restrict__ bq, const float* __restrict__ bk,
    const float* __restrict__ bv,
    const unsigned char* __restrict__ wsp,
    float* __restrict__ out)
{
    __shared__ __align__(16) unsigned char smem[SMEM_BYTES];

    const int b    = blockIdx.x;
    const int tid  = threadIdx.x;
    const int w    = tid >> 6;
    const int lane = tid & 63;
    const int quad = lane >> 4;
    const int nl   = lane & 15;
    const int ri   = w >> 2;
    const int cj   = w & 3;

    f32x4 acc[4][3];
    #pragma unroll
    for (int i = 0; i < 4; ++i)
        #pragma unroll
        for (int j = 0; j < 3; ++j) acc[i][j] = (f32x4){0,0,0,0};

    const float4* x4 = reinterpret_cast<const float4*>(x + (size_t)b * Tt * Ee);

    auto bgld = [&](int ecn) {
        if (w < 12) {
            int p = ecn & 1;
            const unsigned char* ghi = wsp + (size_t)(ecn * 12 + w) * 1024 + (size_t)lane * 16;
            const unsigned char* glo = ghi + WLO_OFF;
            __builtin_amdgcn_global_load_lds(
                (const __attribute__((address_space(1))) unsigned*)ghi,
                (__attribute__((address_space(3))) unsigned*)(smem + BB0 + p * 24576 + w * 1024),
                16, 0, 0);
            __builtin_amdgcn_global_load_lds(
                (const __attribute__((address_space(1))) unsigned*)glo,
                (__attribute__((address_space(3))) unsigned*)(smem + BB0 + p * 24576 + 12288 + w * 1024),
                16, 0, 0);
        }
    };

    const int pt = tid & 255;
    const float4* xp = x4 + pt * 96;
    unsigned char* adst = smem + (pt >> 4) * 1024 + (pt & 15) * 16;
    float4 px[8];

    auto loadX = [&](int ecsrc) {
        const float4* xr_ = xp + ecsrc * 8;
        #pragma unroll
        for (int j = 0; j < 8; ++j) px[j] = xr_[j];
    };
    auto stageWrite = [&](int nb) {
        #pragma unroll
        for (int ko = 0; ko < 4; ++ko) {
            float v0 = px[2*ko+0].x, v1 = px[2*ko+0].y,
                  v2 = px[2*ko+0].z, v3 = px[2*ko+0].w,
                  v4 = px[2*ko+1].x, v5 = px[2*ko+1].y,
                  v6 = px[2*ko+1].z, v7 = px[2*ko+1].w;
            unsigned h0 = cvt_pk_bf16(v0, v1);
            unsigned h1 = cvt_pk_bf16(v2, v3);
            unsigned h2 = cvt_pk_bf16(v4, v5);
            unsigned h3 = cvt_pk_bf16(v6, v7);
            unsigned l0 = cvt_pk_bf16(v0 - __uint_as_float(h0 << 16),
                                      v1 - __uint_as_float(h0 & 0xFFFF0000u));
            unsigned l1 = cvt_pk_bf16(v2 - __uint_as_float(h1 << 16),
                                      v3 - __uint_as_float(h1 & 0xFFFF0000u));
            unsigned l2 = cvt_pk_bf16(v4 - __uint_as_float(h2 << 16),
                                      v5 - __uint_as_float(h2 & 0xFFFF0000u));
            unsigned l3 = cvt_pk_bf16(v6 - __uint_as_float(h3 << 16),
                                      v7 - __uint_as_float(h3 & 0xFFFF0000u));
            u32x4 hv = {h0, h1, h2, h3};
            u32x4 lv = {l0, l1, l2, l3};
            *reinterpret_cast<u32x4*>(adst + nb + ko * 256) = hv;
            *reinterpret_cast<u32x4*>(adst + nb + 16384 + ko * 256) = lv;
        }
    };

    bgld(0);
    if (w >= 12) {
        loadX(0);
        stageWrite(0);
        loadX(1);
    }

    for (int ec = 0; ec < 12; ++ec) {
        __syncthreads();
        if (w < 12) {
            if (ec < 11) bgld(ec + 1);
        } else {
            if (ec < 11) stageWrite((1 - (ec & 1)) * 32768);
            if (ec < 10) loadX(ec + 2);
        }

        const int ab = (ec & 1) * 32768;
        const int bb = BB0 + (ec & 1) * 24576;
        bf16x8 bh[3], bl[3];
        #pragma unroll
        for (int ct = 0; ct < 3; ++ct) {
            int o = bb + (cj * 3 + ct) * 1024 + lane * 16;
            bh[ct] = *reinterpret_cast<bf16x8*>(smem + o);
            bl[ct] = *reinterpret_cast<bf16x8*>(smem + o + 12288);
        }
        __builtin_amdgcn_s_setprio(1);
        #pragma unroll
        for (int rt = 0; rt < 4; ++rt) {
            int ao = ab + (4 * ri + rt) * 1024 + lane * 16;
            bf16x8 ah = *reinterpret_cast<bf16x8*>(smem + ao);
            bf16x8 al = *reinterpret_cast<bf16x8*>(smem + ao + 16384);
            #pragma unroll
            for (int ct = 0; ct < 3; ++ct) {
                acc[rt][ct] = MFMA16(ah, bh[ct], acc[rt][ct]);
                acc[rt][ct] = MFMA16(al, bh[ct], acc[rt][ct]);
                acc[rt][ct] = MFMA16(ah, bl[ct], acc[rt][ct]);
            }
        }
        __builtin_amdgcn_s_setprio(0);
    }
    __syncthreads();

    #pragma unroll
    for (int ct = 0; ct < 3; ++ct) {
        int col = (cj * 3 + ct) * 16 + nl;
        float bias = (col < 64) ? bq[col] : (col < 128 ? bk[col - 64] : bv[col - 128]);
        #pragma unroll
        for (int rt = 0; rt < 4; ++rt)
            #pragma unroll
            for (int r = 0; r < 4; ++r) acc[rt][ct][r] += bias;
    }

    #pragma unroll
    for (int ct = 0; ct < 3; ++ct) {
        int col = (cj * 3 + ct) * 16 + nl;
        #pragma unroll
        for (int rt = 0; rt < 4; ++rt) {
            #pragma unroll
            for (int r = 0; r < 4; ++r) {
                float val = acc[rt][ct][r];
                int s = ri * 64 + rt * 16 + quad * 4 + r;
                if (col >= 64 && col < 128) {
                    int h = col - 64;
                    int addr = ((s >> 4) * 2 + (h >> 5)) * 1024
                             + ((((h & 31) >> 3) * 16 + (s & 15)) * 8 + (h & 7)) * 2;
                    short hi = f2bf(val);
                    short lo = f2bf(val - bf2f(hi));
                    *reinterpret_cast<short*>(smem + K_HI + addr) = hi;
                    *reinterpret_cast<short*>(smem + K_LO + addr) = lo;
                } else if (col >= 128) {
                    int h = col - 128, sl = s & 31;
                    int addr = ((s >> 5) * 4 + (h >> 4)) * 1024
                             + (((sl >> 3) * 16 + (h & 15)) * 8 + (sl & 7)) * 2;
                    *reinterpret_cast<short*>(smem + VF + addr) = f2bf(val);
                }
            }
        }
    }

    auto writeQhalf = [&]() {
        #pragma unroll
        for (int ct = 0; ct < 3; ++ct) {
            int col = (cj * 3 + ct) * 16 + nl;
            if (col < 64) {
                #pragma unroll
                for (int rt = 0; rt < 4; ++rt) {
                    #pragma unroll
                    for (int r = 0; r < 4; ++r) {
                        float val = acc[rt][ct][r];
                        int s = ri * 64 + rt * 16 + quad * 4 + r;
                        int rloc = s & 127;
                        short hi = f2bf(val);
                        short lo = f2bf(val - bf2f(hi));
                        *reinterpret_cast<short*>(smem + QH + (rloc * 72 + col) * 2) = hi;
                        *reinterpret_cast<short*>(smem + QL + (rloc * 72 + col) * 2) = lo;
                    }
                }
            }
        }
    };
    bf16x8 qh0, qh1, ql0, ql1;
    auto readQ = [&]() {
        int rloc = (16 * w + nl) & 127;
        int base = rloc * 144;
        qh0 = *reinterpret_cast<bf16x8*>(smem + QH + base + quad * 16);
        qh1 = *reinterpret_cast<bf16x8*>(smem + QH + base + 64 + quad * 16);
        ql0 = *reinterpret_cast<bf16x8*>(smem + QL + base + quad * 16);
        ql1 = *reinterpret_cast<bf16x8*>(smem + QL + base + 64 + quad * 16);
    };

    if (ri < 2) writeQhalf();
    __syncthreads();
    if (w < 8) readQ();
    __syncthreads();
    if (ri >= 2) writeQhalf();
    __syncthreads();
    if (w >= 8) readQ();
    __syncthreads();

    f32x4 oacc[4];
    #pragma unroll
    for (int i = 0; i < 4; ++i) oacc[i] = (f32x4){0,0,0,0};
    float lsum4[4] = {0.f, 0.f, 0.f, 0.f};
    const int t0 = w * 16;
    unsigned char* pb = smem + PBASE + w * 1344;
    const int npairs = (w >> 1) + 1;

    bf16x8 kA0, kA1, kA2, kA3, kB0, kB1, kB2, kB3;
#define LDK(P) do {                                                     \
        int kb0_ = (2 * (P)) * 2048 + lane * 16;                        \
        kA0 = *reinterpret_cast<bf16x8*>(smem + K_HI + kb0_);           \
        kA1 = *reinterpret_cast<bf16x8*>(smem + K_HI + kb0_ + 1024);    \
        kA2 = *reinterpret_cast<bf16x8*>(smem + K_LO + kb0_);           \
        kA3 = *reinterpret_cast<bf16x8*>(smem + K_LO + kb0_ + 1024);    \
        kB0 = *reinterpret_cast<bf16x8*>(smem + K_HI + kb0_ + 2048);    \
        kB1 = *reinterpret_cast<bf16x8*>(smem + K_HI + kb0_ + 3072);    \
        kB2 = *reinterpret_cast<bf16x8*>(smem + K_LO + kb0_ + 2048);    \
        kB3 = *reinterpret_cast<bf16x8*>(smem + K_LO + kb0_ + 3072);    \
    } while (0)

    LDK(0);
    for (int p = 0; p < npairs; ++p) {
        f32x4 sa0 = (f32x4){0,0,0,0}, sa1 = (f32x4){0,0,0,0};
        f32x4 sb0 = (f32x4){0,0,0,0}, sb1 = (f32x4){0,0,0,0};
        __builtin_amdgcn_s_setprio(1);
        sa0 = MFMA16(qh0, kA0, sa0);  sb0 = MFMA16(qh0, kB0, sb0);
        sa1 = MFMA16(qh1, kA1, sa1);  sb1 = MFMA16(qh1, kB1, sb1);
        sa0 = MFMA16(ql0, kA0, sa0);  sb0 = MFMA16(ql0, kB0, sb0);
        sa1 = MFMA16(ql1, kA1, sa1);  sb1 = MFMA16(ql1, kB1, sb1);
        sa0 = MFMA16(qh0, kA2, sa0);  sb0 = MFMA16(qh0, kB2, sb0);
        sa1 = MFMA16(qh1, kA3, sa1);  sb1 = MFMA16(qh1, kB3, sb1);
        __builtin_amdgcn_s_setprio(0);

        float rs[4];
        const int sg0 = 32 * p + nl, sg1 = sg0 + 16;
        #pragma unroll
        for (int r = 0; r < 4; ++r) {
            int tg = t0 + quad * 4 + r;
            float sva = sa0[r] + sa1[r];
            float svb = sb0[r] + sb1[r];
            float pva = (sg0 <= tg) ? __expf(sva) : 0.f;
            float pvb = (sg1 <= tg) ? __expf(svb) : 0.f;
            rs[r] = pva + pvb;
            *reinterpret_cast<short*>(pb + ((quad * 4 + r) * 40 + nl) * 2)      = f2bf(pva);
            *reinterpret_cast<short*>(pb + ((quad * 4 + r) * 40 + 16 + nl) * 2) = f2bf(pvb);
        }
        asm volatile("" ::: "memory");
        bf16x8 pa  = *reinterpret_cast<bf16x8*>(pb + (nl * 40 + quad * 8) * 2);
        int vb = p * 4096 + lane * 16;
        bf16x8 vf0 = *reinterpret_cast<bf16x8*>(smem + VF + vb);
        bf16x8 vf1 = *reinterpret_cast<bf16x8*>(smem + VF + vb + 1024);
        bf16x8 vf2 = *reinterpret_cast<bf16x8*>(smem + VF + vb + 2048);
        bf16x8 vf3 = *reinterpret_cast<bf16x8*>(smem + VF + vb + 3072);
        if (p + 1 < npairs) LDK(p + 1);

        #pragma unroll
        for (int r = 0; r < 4; ++r) {
            float v = rs[r];
            v += __shfl_xor(v, 1);
            v += __shfl_xor(v, 2);
            v += __shfl_xor(v, 4);
            v += __shfl_xor(v, 8);
            lsum4[r] += v;
        }
        __builtin_amdgcn_s_setprio(1);
        oacc[0] = MFMA16(pa, vf0, oacc[0]);
        oacc[1] = MFMA16(pa, vf1, oacc[1]);
        oacc[2] = MFMA16(pa, vf2, oacc[2]);
        oacc[3] = MFMA16(pa, vf3, oacc[3]);
        __builtin_amdgcn_s_setprio(0);
    }
#undef LDK

    float* ob = out + (size_t)b * Tt * Hh + (size_t)t0 * Hh;
    #pragma unroll
    for (int r = 0; r < 4; ++r) {
        float inv = 1.0f / lsum4[r];
        #pragma unroll
        for (int nt = 0; nt < 4; ++nt)
            ob[(quad * 4 + r) * 64 + nt * 16 + nl] = oacc[nt][r] * inv;
    }
}

extern "C" void kernel_launch(void* const* d_in, const int* in_sizes, int n_in,
                              void* d_out, int out_size, void* d_ws, size_t ws_size,
                              hipStream_t stream) {
    const float* x  = (const float*)d_in[0];
    const float* Wq = (const float*)d_in[1];
    const float* bq = (const float*)d_in[2];
    const float* Wk = (const float*)d_in[3];
    const float* bk = (const float*)d_in[4];
    const float* Wv = (const float*)d_in[5];
    const float* bv = (const float*)d_in[6];
    float* out = (float*)d_out;
    unsigned char* wsp = (unsigned char*)d_ws;
    hipLaunchKernelGGL(prep_w, dim3(36), dim3(256), 0, stream, Wq, Wk, Wv, wsp);
    if (ws_size >= WS_NEED) {
        hipLaunchKernelGGL(qkv_proj, dim3(512), dim3(512), 0, stream,
                           x, bq, bk, bv, wsp, wsp + WQKV);
        hipLaunchKernelGGL(attn, dim3(512), dim3(512), 0, stream,
                           wsp + WQKV, out);
    } else {
        hipLaunchKernelGGL(head_fused, dim3(Bb), dim3(1024), 0, stream,
                           x, bq, bk, bv, wsp, out);
    }
}

// Round 7
// 184.049 us; speedup vs baseline: 1.0531x; 1.0531x over previous
//
#include <hip/hip_runtime.h>
#include <math.h>

#define Bb 256
#define Tt 256
#define Ee 384
#define Hh 64

typedef __attribute__((ext_vector_type(8))) short bf16x8;
typedef __attribute__((ext_vector_type(4))) float f32x4;
typedef __attribute__((ext_vector_type(4))) unsigned int u32x4;

__device__ inline short f2bf(float f) {
    unsigned u = __float_as_uint(f);
    u += 0x7FFFu + ((u >> 16) & 1);      // RNE
    return (short)(u >> 16);
}
__device__ inline float bf2f(short s) {
    return __uint_as_float(((unsigned)(unsigned short)s) << 16);
}
// packed f32x2 -> bf16x2 (RNE). D[15:0]=bf16(a), D[31:16]=bf16(b)
__device__ inline unsigned cvt_pk_bf16(float a, float b) {
    unsigned r;
    asm("v_cvt_pk_bf16_f32 %0, %1, %2" : "=v"(r) : "v"(a), "v"(b));
    return r;
}
__device__ inline float lo16f(unsigned u) { return __uint_as_float(u << 16); }
__device__ inline float hi16f(unsigned u) { return __uint_as_float(u & 0xFFFF0000u); }

#define MFMA16(a, b, c) __builtin_amdgcn_mfma_f32_16x16x32_bf16((a), (b), (c), 0, 0, 0)

// ---- W fragment buffer in d_ws: hi at 0, lo at 147456; frag (ec*12+tct)*1024 ----
#define WLO_OFF 147456

// ---- LDS byte offsets ----
// phase 1: A dbuf at p*32768 (hi) / +16384 (lo); B dbuf at 65536 + p*24576 (hi) / +12288 (lo)
#define BB0 65536
// phase 2 (live after phase 1):
#define K_HI 0
#define K_LO 32768
#define VF   65536
#define QH   98304
#define QL   116736
#define PBASE 98304
#define SMEM_BYTES 135168

// ============ prep kernel: W -> bf16 hi/lo in B-fragment layout (coalesced) ============
__global__ __launch_bounds__(256) void prep_w(
    const float* __restrict__ Wq, const float* __restrict__ Wk,
    const float* __restrict__ Wv, unsigned char* __restrict__ wsp)
{
    __shared__ float wlds[32 * 66];
    const int bid = blockIdx.x;                // 0..35
    const int ec  = bid / 3, m = bid - ec * 3;
    const float* Wm = (m == 0) ? Wq : (m == 1 ? Wk : Wv);
    const int tid = threadIdx.x;

    const float4* src = reinterpret_cast<const float4*>(Wm + ec * 2048) + tid * 2;
    float4 a = src[0], b = src[1];
    int f = tid * 8;
    float* d = wlds + (f >> 6) * 66 + (f & 63);
    d[0] = a.x; d[1] = a.y; d[2] = a.z; d[3] = a.w;
    d[4] = b.x; d[5] = b.y; d[6] = b.z; d[7] = b.w;
    __syncthreads();

    const int tl = tid >> 6, lu = tid & 63;
    const int koct = lu >> 4, n = lu & 15;
    const int c = tl * 16 + n;
    bf16x8 hi8, lo8;
    #pragma unroll
    for (int j = 0; j < 8; ++j) {
        float v = wlds[(koct * 8 + j) * 66 + c];
        short h = f2bf(v);
        hi8[j] = h;
        lo8[j] = f2bf(v - bf2f(h));
    }
    const int frag = ec * 12 + m * 4 + tl;
    *reinterpret_cast<bf16x8*>(wsp + frag * 1024 + lu * 16) = hi8;
    *reinterpret_cast<bf16x8*>(wsp + WLO_OFF + frag * 1024 + lu * 16) = lo8;
}

// ============ main fused kernel: producer/consumer phase-1 ============
// waves 0-11: consumers. rg=w&3 -> rowtiles 4rg..4rg+3; cg=w>>2 -> coltiles 4cg..4cg+3
//             (cg=0: Q cols 0-63, cg=1: K cols 64-127, cg=2: V cols 128-191).
// waves 12-15: producers. All B-frag DMA (3 frag-pairs each) + A staging; no MFMA.
__global__ __launch_bounds__(1024) void head_fused(
    const float* __restrict__ x,
    const float* __restrict__ bq, const float* __restrict__ bk,
    const float* __restrict__ bv,
    const unsigned char* __restrict__ wsp,
    float* __restrict__ out)
{
    __shared__ __align__(16) unsigned char smem[SMEM_BYTES];

    const int b    = blockIdx.x;
    const int tid  = threadIdx.x;
    const int w    = tid >> 6;        // wave 0..15
    const int lane = tid & 63;
    const int quad = lane >> 4;
    const int nl   = lane & 15;
    const bool producer = (w >= 12);
    const int rg   = w & 3;           // consumer rowgroup
    const int cg   = w >> 2;          // consumer colgroup (0..2)

    f32x4 acc[4][4];
    #pragma unroll
    for (int i = 0; i < 4; ++i)
        #pragma unroll
        for (int j = 0; j < 4; ++j) acc[i][j] = (f32x4){0,0,0,0};

    const float4* x4 = reinterpret_cast<const float4*>(x + (size_t)b * Tt * Ee);

    // producer-issued B-frag DMA: producer (w-12) moves frag-pairs 3(w-12)..+2
    auto bgld = [&](int ecn) {
        int p = ecn & 1;
        int f0 = (w - 12) * 3;
        #pragma unroll
        for (int j = 0; j < 3; ++j) {
            const unsigned char* g = wsp + (size_t)(ecn * 12 + f0 + j) * 1024 + (size_t)lane * 16;
            unsigned char* dlds = smem + BB0 + p * 24576 + (f0 + j) * 1024;
            __builtin_amdgcn_global_load_lds(
                (const __attribute__((address_space(1))) unsigned*)g,
                (__attribute__((address_space(3))) unsigned*)dlds, 16, 0, 0);
            __builtin_amdgcn_global_load_lds(
                (const __attribute__((address_space(1))) unsigned*)(g + WLO_OFF),
                (__attribute__((address_space(3))) unsigned*)(dlds + 12288), 16, 0, 0);
        }
    };

    // A staging (producers): thread pt owns x row pt; load 8 float4, convert, write.
    const int pt = tid & 255;
    const float4* xp = x4 + pt * 96;
    unsigned char* adst = smem + (pt >> 4) * 1024 + (pt & 15) * 16;

    auto stageA = [&](int ecsrc, int nb) {
        float4 px[8];
        const float4* xr_ = xp + ecsrc * 8;
        #pragma unroll
        for (int j = 0; j < 8; ++j) px[j] = xr_[j];
        #pragma unroll
        for (int ko = 0; ko < 4; ++ko) {
            float v0 = px[2*ko+0].x, v1 = px[2*ko+0].y,
                  v2 = px[2*ko+0].z, v3 = px[2*ko+0].w,
                  v4 = px[2*ko+1].x, v5 = px[2*ko+1].y,
                  v6 = px[2*ko+1].z, v7 = px[2*ko+1].w;
            unsigned h0 = cvt_pk_bf16(v0, v1);
            unsigned h1 = cvt_pk_bf16(v2, v3);
            unsigned h2 = cvt_pk_bf16(v4, v5);
            unsigned h3 = cvt_pk_bf16(v6, v7);
            unsigned l0 = cvt_pk_bf16(v0 - lo16f(h0), v1 - hi16f(h0));
            unsigned l1 = cvt_pk_bf16(v2 - lo16f(h1), v3 - hi16f(h1));
            unsigned l2 = cvt_pk_bf16(v4 - lo16f(h2), v5 - hi16f(h2));
            unsigned l3 = cvt_pk_bf16(v6 - lo16f(h3), v7 - hi16f(h3));
            u32x4 hv = {h0, h1, h2, h3};
            u32x4 lv = {l0, l1, l2, l3};
            *reinterpret_cast<u32x4*>(adst + nb + ko * 256) = hv;
            *reinterpret_cast<u32x4*>(adst + nb + 16384 + ko * 256) = lv;
        }
    };

    // ---- preloop: producers issue B(0) DMA + stage A(0) ----
    if (producer) {
        bgld(0);
        stageA(0, 0);
    }

    // ================= Phase 1: one barrier per ec =================
    // Consumers: barrier -> ds_read -> MFMA (zero memory-issue work).
    // Producers: barrier -> B-DMA(ec+1) -> stage A(ec+1). No MFMA.
    for (int ec = 0; ec < 12; ++ec) {
        __syncthreads();   // producer vmcnt(0) drain publishes B(ec)+A(ec)
        if (producer) {
            if (ec < 11) {
                bgld(ec + 1);
                stageA(ec + 1, (1 - (ec & 1)) * 32768);
            }
        } else {
            const int ab = (ec & 1) * 32768;
            const int bb = BB0 + (ec & 1) * 24576;
            bf16x8 bh[4], bl[4];
            #pragma unroll
            for (int ct = 0; ct < 4; ++ct) {
                int o = bb + (cg * 4 + ct) * 1024 + lane * 16;
                bh[ct] = *reinterpret_cast<bf16x8*>(smem + o);
                bl[ct] = *reinterpret_cast<bf16x8*>(smem + o + 12288);
            }
            __builtin_amdgcn_s_setprio(1);
            #pragma unroll
            for (int rt = 0; rt < 4; ++rt) {
                int ao = ab + (rg * 4 + rt) * 1024 + lane * 16;
                bf16x8 ah = *reinterpret_cast<bf16x8*>(smem + ao);
                bf16x8 al = *reinterpret_cast<bf16x8*>(smem + ao + 16384);
                #pragma unroll
                for (int ct = 0; ct < 4; ++ct) {
                    acc[rt][ct] = MFMA16(ah, bh[ct], acc[rt][ct]);
                    acc[rt][ct] = MFMA16(al, bh[ct], acc[rt][ct]);
                    acc[rt][ct] = MFMA16(ah, bl[ct], acc[rt][ct]);
                }
            }
            __builtin_amdgcn_s_setprio(0);
        }
    }
    __syncthreads();   // staging dead; phase-2 regions go live

    // ---- bias fold + K/V scatter (consumers; cg-uniform) ----
    if (!producer) {
        const float* bias_m = (cg == 0) ? bq : (cg == 1 ? bk : bv);
        #pragma unroll
        for (int ct = 0; ct < 4; ++ct) {
            float bias = bias_m[ct * 16 + nl];
            #pragma unroll
            for (int rt = 0; rt < 4; ++rt)
                #pragma unroll
                for (int r = 0; r < 4; ++r) acc[rt][ct][r] += bias;
        }

        if (cg == 1) {
            // K scatter (hi/lo), h = ct*16+nl, s = rg*64+rt*16+quad*4+r; r -> +16B
            #pragma unroll
            for (int ct = 0; ct < 4; ++ct) {
                int h = ct * 16 + nl;
                #pragma unroll
                for (int rt = 0; rt < 4; ++rt) {
                    f32x4 v = acc[rt][ct];
                    unsigned h01 = cvt_pk_bf16(v[0], v[1]);
                    unsigned h23 = cvt_pk_bf16(v[2], v[3]);
                    unsigned l01 = cvt_pk_bf16(v[0] - lo16f(h01), v[1] - hi16f(h01));
                    unsigned l23 = cvt_pk_bf16(v[2] - lo16f(h23), v[3] - hi16f(h23));
                    int a0 = ((rg * 4 + rt) * 2 + (h >> 5)) * 1024
                           + ((((h & 31) >> 3) * 16 + quad * 4) * 8 + (h & 7)) * 2;
                    *reinterpret_cast<short*>(smem + K_HI + a0)      = (short)h01;
                    *reinterpret_cast<short*>(smem + K_HI + a0 + 16) = (short)(h01 >> 16);
                    *reinterpret_cast<short*>(smem + K_HI + a0 + 32) = (short)h23;
                    *reinterpret_cast<short*>(smem + K_HI + a0 + 48) = (short)(h23 >> 16);
                    *reinterpret_cast<short*>(smem + K_LO + a0)      = (short)l01;
                    *reinterpret_cast<short*>(smem + K_LO + a0 + 16) = (short)(l01 >> 16);
                    *reinterpret_cast<short*>(smem + K_LO + a0 + 32) = (short)l23;
                    *reinterpret_cast<short*>(smem + K_LO + a0 + 48) = (short)(l23 >> 16);
                }
            }
        } else if (cg == 2) {
            // V scatter (bf16): consecutive r are contiguous shorts -> 2x b32 store
            #pragma unroll
            for (int ct = 0; ct < 4; ++ct) {
                int h = ct * 16 + nl;
                #pragma unroll
                for (int rt = 0; rt < 4; ++rt) {
                    f32x4 v = acc[rt][ct];
                    unsigned h01 = cvt_pk_bf16(v[0], v[1]);
                    unsigned h23 = cvt_pk_bf16(v[2], v[3]);
                    int s29 = rg * 2 + (rt >> 1);                  // s>>5
                    int slh = (rt & 1) * 2 + (quad >> 1);          // sl>>3
                    int sl7 = (quad & 1) * 4;                      // sl&7 (r=0)
                    int a0 = (s29 * 4 + (h >> 4)) * 1024
                           + ((slh * 16 + (h & 15)) * 8 + sl7) * 2;
                    *reinterpret_cast<unsigned*>(smem + VF + a0)     = h01;
                    *reinterpret_cast<unsigned*>(smem + VF + a0 + 4) = h23;
                }
            }
        }
    }

    // ---- Q round-trip through LDS, two half-phases (cg==0 waves write) ----
    auto writeQhalf = [&]() {
        #pragma unroll
        for (int ct = 0; ct < 4; ++ct) {
            int col = ct * 16 + nl;
            #pragma unroll
            for (int rt = 0; rt < 4; ++rt) {
                f32x4 v = acc[rt][ct];
                unsigned h01 = cvt_pk_bf16(v[0], v[1]);
                unsigned h23 = cvt_pk_bf16(v[2], v[3]);
                unsigned l01 = cvt_pk_bf16(v[0] - lo16f(h01), v[1] - hi16f(h01));
                unsigned l23 = cvt_pk_bf16(v[2] - lo16f(h23), v[3] - hi16f(h23));
                int s0 = rg * 64 + rt * 16 + quad * 4;
                int a0 = ((s0 & 127) * 72 + col) * 2;              // r -> +144B
                *reinterpret_cast<short*>(smem + QH + a0)       = (short)h01;
                *reinterpret_cast<short*>(smem + QH + a0 + 144) = (short)(h01 >> 16);
                *reinterpret_cast<short*>(smem + QH + a0 + 288) = (short)h23;
                *reinterpret_cast<short*>(smem + QH + a0 + 432) = (short)(h23 >> 16);
                *reinterpret_cast<short*>(smem + QL + a0)       = (short)l01;
                *reinterpret_cast<short*>(smem + QL + a0 + 144) = (short)(l01 >> 16);
                *reinterpret_cast<short*>(smem + QL + a0 + 288) = (short)l23;
                *reinterpret_cast<short*>(smem + QL + a0 + 432) = (short)(l23 >> 16);
            }
        }
    };
    bf16x8 qh0, qh1, ql0, ql1;
    auto readQ = [&]() {
        int rloc = (16 * w + nl) & 127;
        int base = rloc * 144;
        qh0 = *reinterpret_cast<bf16x8*>(smem + QH + base + quad * 16);
        qh1 = *reinterpret_cast<bf16x8*>(smem + QH + base + 64 + quad * 16);
        ql0 = *reinterpret_cast<bf16x8*>(smem + QL + base + quad * 16);
        ql1 = *reinterpret_cast<bf16x8*>(smem + QL + base + 64 + quad * 16);
    };

    if (!producer && cg == 0 && rg < 2) writeQhalf();   // rows 0..127
    __syncthreads();
    if (w < 8) readQ();
    __syncthreads();
    if (!producer && cg == 0 && rg >= 2) writeQhalf();  // rows 128..255
    __syncthreads();
    if (w >= 8) readQ();
    __syncthreads();

    // ================= Phase 2: causal attention, wave w owns rows 16w..16w+15 =================
    f32x4 oacc[4];
    #pragma unroll
    for (int i = 0; i < 4; ++i) oacc[i] = (f32x4){0,0,0,0};
    float lsum = 0.f;
    const int t0 = w * 16;
    unsigned char* pb = smem + PBASE + w * 1344;
    const int npairs = (w >> 1) + 1;

    for (int p = 0; p < npairs; ++p) {
        #pragma unroll
        for (int hf = 0; hf < 2; ++hf) {
            int st = 2 * p + hf;
            f32x4 s0 = (f32x4){0,0,0,0}, s1 = (f32x4){0,0,0,0};
            int kb = st * 2048 + lane * 16;
            bf16x8 kh0 = *reinterpret_cast<bf16x8*>(smem + K_HI + kb);
            bf16x8 kh1 = *reinterpret_cast<bf16x8*>(smem + K_HI + kb + 1024);
            bf16x8 kl0 = *reinterpret_cast<bf16x8*>(smem + K_LO + kb);
            bf16x8 kl1 = *reinterpret_cast<bf16x8*>(smem + K_LO + kb + 1024);
            s0 = MFMA16(qh0, kh0, s0);
            s1 = MFMA16(qh1, kh1, s1);
            s0 = MFMA16(ql0, kh0, s0);
            s1 = MFMA16(ql1, kh1, s1);
            s0 = MFMA16(qh0, kl0, s0);
            s1 = MFMA16(qh1, kl1, s1);
            int sg = st * 16 + nl;
            #pragma unroll
            for (int r = 0; r < 4; ++r) {
                int tg = t0 + quad * 4 + r;
                float sv = s0[r] + s1[r];
                float pv = (sg <= tg) ? __expf(sv) : 0.f;
                *reinterpret_cast<short*>(pb + ((quad * 4 + r) * 40 + hf * 16 + nl) * 2) = f2bf(pv);
            }
        }
        asm volatile("s_waitcnt lgkmcnt(0)" ::: "memory");
        bf16x8 pa = *reinterpret_cast<bf16x8*>(pb + (nl * 40 + quad * 8) * 2);
        float ls = 0.f;
        #pragma unroll
        for (int j = 0; j < 8; ++j) ls += bf2f(pa[j]);
        ls += __shfl_xor(ls, 16);
        ls += __shfl_xor(ls, 32);
        lsum += ls;
        int vb = p * 4096 + lane * 16;
        #pragma unroll
        for (int nt = 0; nt < 4; ++nt) {
            bf16x8 vf = *reinterpret_cast<bf16x8*>(smem + VF + vb + nt * 1024);
            oacc[nt] = MFMA16(pa, vf, oacc[nt]);
        }
    }

    // ---- normalize + write out ----
    float* lb_ = reinterpret_cast<float*>(pb + 1280);
    if (lane < 16) lb_[lane] = lsum;
    asm volatile("s_waitcnt lgkmcnt(0)" ::: "memory");
    float* ob = out + (size_t)b * Tt * Hh + (size_t)t0 * Hh;
    #pragma unroll
    for (int r = 0; r < 4; ++r) {
        float inv = 1.0f / lb_[quad * 4 + r];
        #pragma unroll
        for (int nt = 0; nt < 4; ++nt)
            ob[(quad * 4 + r) * 64 + nt * 16 + nl] = oacc[nt][r] * inv;
    }
}

extern "C" void kernel_launch(void* const* d_in, const int* in_sizes, int n_in,
                              void* d_out, int out_size, void* d_ws, size_t ws_size,
                              hipStream_t stream) {
    const float* x  = (const float*)d_in[0];
    const float* Wq = (const float*)d_in[1];
    const float* bq = (const float*)d_in[2];
    const float* Wk = (const float*)d_in[3];
    const float* bk = (const float*)d_in[4];
    const float* Wv = (const float*)d_in[5];
    const float* bv = (const float*)d_in[6];
    float* out = (float*)d_out;
    unsigned char* wsp = (unsigned char*)d_ws;   // needs 294912 B
    hipLaunchKernelGGL(prep_w, dim3(36), dim3(256), 0, stream, Wq, Wk, Wv, wsp);
    hipLaunchKernelGGL(head_fused, dim3(Bb), dim3(1024), 0, stream,
                       x, bq, bk, bv, wsp, out);
}